// Round 12
// baseline (651.791 us; speedup 1.0000x reference)
//
#include <hip/hip_runtime.h>
#include <hip/hip_bf16.h>
#include <hip/hip_cooperative_groups.h>

namespace cg = cooperative_groups;

#define C_ 256
#define H_ 64
#define W_ 64
#define N_ 16
#define HW_ 4096
#define IMG_ (C_ * HW_)          // 1048576 elems (fp32 image)
#define PADIMG_ (66 * 66 * 256)  // 1115136 shorts per padded NHWC image
#define WT_ELEMS_ (9 * 16 * 256 * 16)

typedef short bf16x8 __attribute__((ext_vector_type(8)));
typedef float f32x16 __attribute__((ext_vector_type(16)));

__device__ __forceinline__ unsigned short f2bf(float f) {
  __hip_bfloat16 h = __float2bfloat16(f);  // RTNE
  return *reinterpret_cast<unsigned short*>(&h);
}

__device__ __forceinline__ void gld_lds16(const void* g, void* l) {
  __builtin_amdgcn_global_load_lds(
      (const __attribute__((address_space(1))) void*)g,
      (__attribute__((address_space(3))) void*)l, 16, 0, 0);
}

// ---------------------------------------------------------------------------
// xpad unit: one (h,img) row -> padded-NHWC-bf16 + mask logits (fp64,
// sign-exact). float4 loads; LDS transpose [px][260]; [16][64] fp64 reduce.
// Does NOT write halos (callers handle). smraw: >= 42496 B.
// ---------------------------------------------------------------------------
__device__ __forceinline__ void xpad_unit(
    const float* __restrict__ xn, const float* __restrict__ wm,
    const float* __restrict__ bm, short* __restrict__ Xp,
    unsigned char* __restrict__ mn, int u, short* smraw) {
  unsigned short* lds = (unsigned short*)smraw;            // 33280 B
  double* dsum = (double*)((char*)smraw + 33280);          // 8192 B [16][64]
  float* wms = (float*)((char*)smraw + 41472);             // 1024 B
  const int h = u & 63, img = u >> 6;
  const int tid = threadIdx.x;
  const int pxq = tid & 15, cg = tid >> 4;
  const int p0 = pxq * 4;
  __syncthreads();  // LDS may be in use by previous unit/phase reader
  wms[tid] = wm[tid];
  __syncthreads();
  const float* xi = xn + (size_t)img * IMG_ + h * 64;
  double s0 = 0.0, s1 = 0.0, s2 = 0.0, s3 = 0.0;
#pragma unroll
  for (int i = 0; i < 16; ++i) {
    const int c = cg * 16 + i;
    const float4 v = *(const float4*)&xi[(size_t)c * HW_ + p0];
    lds[(p0 + 0) * 260 + c] = f2bf(v.x);
    lds[(p0 + 1) * 260 + c] = f2bf(v.y);
    lds[(p0 + 2) * 260 + c] = f2bf(v.z);
    lds[(p0 + 3) * 260 + c] = f2bf(v.w);
    const double wmc = (double)wms[c];
    s0 += (double)v.x * wmc;
    s1 += (double)v.y * wmc;
    s2 += (double)v.z * wmc;
    s3 += (double)v.w * wmc;
  }
  dsum[cg * 64 + p0 + 0] = s0;
  dsum[cg * 64 + p0 + 1] = s1;
  dsum[cg * 64 + p0 + 2] = s2;
  dsum[cg * 64 + p0 + 3] = s3;
  __syncthreads();
  short* Xpi = Xp + (size_t)img * PADIMG_ + ((h + 1) * 66 + 1) * 256;
  const int wv = tid >> 6, wl = tid & 63;
#pragma unroll
  for (int j = 0; j < 16; ++j) {
    int w = j * 4 + wv;
    int c4 = wl * 4;
    uint2 d = *(const uint2*)&lds[w * 260 + c4];
    *(uint2*)&Xpi[(size_t)w * 256 + c4] = d;
  }
  if (tid < 64) {
    double t = (double)bm[0];
#pragma unroll
    for (int g = 0; g < 16; ++g) t += dsum[g * 64 + tid];
    mn[img * HW_ + h * 64 + tid] = (t > 0.0) ? 1 : 0;
  }
}

// ---------------------------------------------------------------------------
// Standalone xpadmask (fallback path) == round-11 behavior incl. Xp halo.
// ---------------------------------------------------------------------------
__global__ __launch_bounds__(256) void xpadmask_kernel(
    const float* __restrict__ x, const float* __restrict__ wm,
    const float* __restrict__ bm, short* __restrict__ Xp,
    unsigned char* __restrict__ mask) {
  __shared__ __align__(16) short smx[21248];  // 42496 B
  const int h = blockIdx.x, img = blockIdx.y;
  const int tid = threadIdx.x;
  xpad_unit(x, wm, bm, Xp, mask, img * 64 + h, smx);
  short* Xpimg = Xp + (size_t)img * PADIMG_;
  if (tid < 128) {
    const int side = tid >> 6;
    const int e = (tid & 63) * 4;
    *(uint2*)&Xpimg[((size_t)(h + 1) * 66 + side * 65) * 256 + e] =
        make_uint2(0u, 0u);
  }
  if (h == 0 || h == 63) {
    uint2* rowp = (uint2*)(Xpimg + (size_t)((h == 0) ? 0 : 65) * 66 * 256);
    for (int o = tid; o < 66 * 256 / 4; o += 256) rowp[o] = make_uint2(0u, 0u);
  }
}

// ---------------------------------------------------------------------------
// Fallback: fused weight transform + Hp-halo zero (round 11).
// ---------------------------------------------------------------------------
__global__ __launch_bounds__(256) void wt_halo_kernel(
    const float* __restrict__ w1, const float* __restrict__ w2,
    short* __restrict__ Wt1, short* __restrict__ Wt2,
    short* __restrict__ Hp) {
  const int bx = blockIdx.x;
  const int tid = threadIdx.x;
  if (bx < 512) {
    const int k = bx & 255, which = bx >> 8;
    const float* src = which ? w2 : w1;
    short* dst = which ? Wt2 : Wt1;
    const float* s = src + ((size_t)k * 256 + tid) * 9;
    const int kc = tid >> 4, ce = tid & 15;
#pragma unroll
    for (int t = 0; t < 9; ++t)
      dst[(((size_t)t * 16 + kc) * 256 + k) * 16 + ce] = (short)f2bf(s[t]);
  } else {
    const int img = bx - 512;
    short* Hpi = Hp + (size_t)img * PADIMG_;
    for (int q = tid; q < 260 * 32; q += 256) {
      const int p = q >> 5, seg = q & 31;
      int r, c;
      if (p < 66) { r = 0; c = p; }
      else if (p < 132) { r = 65; c = p - 66; }
      else if (p < 196) { r = p - 131; c = 0; }
      else { r = p - 195; c = 65; }
      uint4* d = (uint4*)(Hpi + (size_t)(r * 66 + c) * 256);
      d[seg] = make_uint4(0u, 0u, 0u, 0u);
    }
  }
}

// ---------------------------------------------------------------------------
// Implicit-GEMM 3x3 conv unit (v9/v11 verified K-loop, 88-91us/dispatch).
// Frozen: 5 structural variants converged 87-91us; see round 8-10 notes.
// Block-unit: 64 out-ch x 512 px, 4 waves; acc[2][4] = 128 AGPR;
// W+B double-buffered LDS (79104 B); stage burst at kk top; single
// end-of-kk vmcnt(0)+s_barrier; 1-tap LDS lookahead, compile-time offsets.
// epi 0: dstH[padded NHWC] = g ? relu(acc) : 0  (g = 3x3 OR mask, fused dil)
// epi 1: dstF[NCHW fp32]   = xres + (g ? relu(acc):0)  (g = std mask)
// ---------------------------------------------------------------------------
#define BBUF 10560   // shorts per B buffer (2 K-halves x 660 slots x 8)
#define WOFF 21120   // 2 * BBUF
#define WBUF 9216    // shorts per W buffer (9 taps x 2 ihalf x 64 ch x 8)

__device__ __forceinline__ void stage_BW(short* sm, int buf, const short* Xb,
                                         const short* Wg, int ch0, int kc,
                                         int wave, int lane) {
  short* Bd = sm + buf * BBUF;
  short* Wd = sm + WOFF + buf * WBUF;
  const int ko = kc * 16;
#pragma unroll
  for (int q = 0; q < 10; ++q) {
    const int n = wave + 4 * q;
    if (n < 22) {
      const int h = (n >= 11) ? 1 : 0;
      const int i = n - h * 11;
      const int row0 = (i < 10) ? i * 64 : 596;
      gld_lds16(Xb + (size_t)(row0 + lane) * 256 + ko + h * 8,
                Bd + h * 5280 + row0 * 8);
    } else {
      const int m = n - 22;
      const int t = m >> 1, ih = m & 1;
      gld_lds16(Wg + (((size_t)t * 16 + kc) * 256 + ch0 + ih * 32 +
                      (lane & 31)) * 16 + (lane >> 5) * 8,
                Wd + (t * 2 + ih) * 512);
    }
  }
}

__device__ __forceinline__ void conv_unit(
    int d, int swz, const short* __restrict__ src, const short* __restrict__ Wt,
    const unsigned char* __restrict__ gate, const float* __restrict__ xres,
    short* __restrict__ dstH, float* __restrict__ dstF, int epi, short* sm) {
  const int tid = threadIdx.x;
  const int lane = tid & 63, wave = tid >> 6;  // 4 waves
  const int ln31 = lane & 31, kh = lane >> 5;

  int bx, by, bz;
  if (swz) {
    int k = d & 7, j = d >> 3;
    bx = j & 3;
    by = (j >> 2) & 7;
    bz = ((j >> 5) << 3) + k;
  } else {
    bx = d & 3;
    by = (d >> 2) & 7;
    bz = d >> 5;
  }
  const int ch0 = bx * 64;
  const int h0 = by * 8;
  const int img = bz;

  const short* Xb = src + (size_t)img * PADIMG_ + (size_t)(h0 * 66) * 256;

  f32x16 acc[2][4];
#pragma unroll
  for (int i = 0; i < 2; ++i)
#pragma unroll
    for (int j = 0; j < 4; ++j)
#pragma unroll
      for (int e = 0; e < 16; ++e) acc[i][j][e] = 0.f;

  stage_BW(sm, 0, Xb, Wt, ch0, 0, wave, lane);
  asm volatile("s_waitcnt vmcnt(0)\n\ts_barrier" ::: "memory");

  for (int kk = 0; kk < 16; ++kk) {
    const int cur = kk & 1;
    if (kk < 15) stage_BW(sm, cur ^ 1, Xb, Wt, ch0, kk + 1, wave, lane);

    const short* Bth = sm + cur * BBUF + kh * 5280 + (wave * 132 + ln31) * 8;
    const short* Wth = sm + WOFF + cur * WBUF + (kh * 32 + ln31) * 8;

    bf16x8 ac[2], bc[4], an[2], bn[4];
#pragma unroll
    for (int i = 0; i < 2; ++i)
      ac[i] = *(const bf16x8*)(Wth + i * 512);
#pragma unroll
    for (int j = 0; j < 4; ++j)
      bc[j] = *(const bf16x8*)(Bth + ((j >> 1) * 66 + (j & 1) * 32) * 8);

#pragma unroll
    for (int t = 0; t < 9; ++t) {
      if (t < 8) {
        const int dy = (t + 1) / 3, dx = (t + 1) % 3;
#pragma unroll
        for (int i = 0; i < 2; ++i)
          an[i] = *(const bf16x8*)(Wth + ((t + 1) * 2 + i) * 512);
#pragma unroll
        for (int j = 0; j < 4; ++j)
          bn[j] = *(const bf16x8*)(Bth +
                                   (((j >> 1) + dy) * 66 + (j & 1) * 32 + dx) * 8);
      }
      __builtin_amdgcn_s_setprio(1);
#pragma unroll
      for (int j = 0; j < 4; ++j) {
        acc[0][j] = __builtin_amdgcn_mfma_f32_32x32x16_bf16(ac[0], bc[j],
                                                            acc[0][j], 0, 0, 0);
        acc[1][j] = __builtin_amdgcn_mfma_f32_32x32x16_bf16(ac[1], bc[j],
                                                            acc[1][j], 0, 0, 0);
      }
      __builtin_amdgcn_s_setprio(0);
      if (t < 8) {
#pragma unroll
        for (int i = 0; i < 2; ++i) ac[i] = an[i];
#pragma unroll
        for (int j = 0; j < 4; ++j) bc[j] = bn[j];
      }
    }
    if (kk < 15)
      asm volatile("s_waitcnt vmcnt(0)\n\ts_barrier" ::: "memory");
  }

  const int rb = h0 + wave * 2;
#pragma unroll
  for (int j = 0; j < 4; ++j) {
    const int r = rb + (j >> 1);
    const int col = (j & 1) * 32 + ln31;
    const int pidx = r * 64 + col;
    unsigned int g;
    if (epi == 0) {
      g = 0;
#pragma unroll
      for (int dy = -1; dy <= 1; ++dy) {
        const int rr = r + dy;
        if (rr < 0 || rr >= H_) continue;
#pragma unroll
        for (int dx = -1; dx <= 1; ++dx) {
          const int cc = col + dx;
          if (cc < 0 || cc >= W_) continue;
          g |= gate[img * HW_ + rr * W_ + cc];
        }
      }
    } else {
      g = gate[img * HW_ + pidx];
    }
#pragma unroll
    for (int i = 0; i < 2; ++i) {
      const f32x16 v = acc[i][j];
#pragma unroll
      for (int rg = 0; rg < 4; ++rg) {
        const int ch = ch0 + i * 32 + rg * 8 + kh * 4;
        float e0 = g ? fmaxf(v[rg * 4 + 0], 0.f) : 0.f;
        float e1 = g ? fmaxf(v[rg * 4 + 1], 0.f) : 0.f;
        float e2 = g ? fmaxf(v[rg * 4 + 2], 0.f) : 0.f;
        float e3 = g ? fmaxf(v[rg * 4 + 3], 0.f) : 0.f;
        if (epi == 0) {
          uint2 u;
          u.x = (unsigned int)f2bf(e0) | ((unsigned int)f2bf(e1) << 16);
          u.y = (unsigned int)f2bf(e2) | ((unsigned int)f2bf(e3) << 16);
          short* dp = dstH + (size_t)img * PADIMG_ +
                      ((size_t)((r + 1) * 66 + (col + 1))) * 256 + ch;
          *(uint2*)dp = u;
        } else {
          size_t o = (size_t)img * IMG_ + (size_t)ch * HW_ + pidx;
          dstF[o] = xres[o] + e0;
          dstF[o + HW_] = xres[o + HW_] + e1;
          dstF[o + 2 * HW_] = xres[o + 2 * HW_] + e2;
          dstF[o + 3 * HW_] = xres[o + 3 * HW_] + e3;
        }
      }
    }
  }
}

// Fallback per-launch conv kernel (round-11 behavior).
template <int EPI>
__global__ __launch_bounds__(256, 2) void conv_mfma(
    const short* __restrict__ src, const short* __restrict__ Wt,
    const unsigned char* __restrict__ gate, const float* __restrict__ xres,
    short* __restrict__ dstH, float* __restrict__ dstF, int swz) {
  __shared__ __align__(16) short sm[2 * BBUF + 2 * WBUF];
  const int d = blockIdx.x + 4 * (blockIdx.y + 8 * blockIdx.z);
  conv_unit(d, swz, src, Wt, gate, xres, dstH, dstF, EPI, sm);
}

// ---------------------------------------------------------------------------
// Cooperative mega-kernel: {wt+halos} -> per chunk {xpad -> conv0 -> conv1},
// phases separated by grid.sync(). Round-11 accounting: non-conv = 103us but
// modeled kernel time ~45us -> ~55us is per-launch overhead (4 launches).
// One launch removes it; conv phases are byte-identical to the frozen v9
// K-loop. 512 blocks x 256 thr = exactly 2 blocks/CU (LDS 79104x2 <= 160K,
// 128 VGPR + 128 AGPR x 2 waves/SIMD = full RF) -> co-residency guaranteed
// by the cooperative launch (fails, not hangs, if not).
// ---------------------------------------------------------------------------
__global__ __launch_bounds__(256, 2) void mega(
    const float* __restrict__ x, const float* __restrict__ w1,
    const float* __restrict__ w2, const float* __restrict__ wm,
    const float* __restrict__ bm, float* __restrict__ out,
    unsigned char* __restrict__ mask, short* __restrict__ Wt1,
    short* __restrict__ Wt2, short* __restrict__ Xp, short* __restrict__ Hp,
    int B) {
  __shared__ __align__(16) short sm[2 * BBUF + 2 * WBUF];  // 79104 B
  cg::grid_group grid = cg::this_grid();
  const int b = blockIdx.x;  // 0..511
  const int tid = threadIdx.x;

  // Phase A: weight transform (all 512 blocks) + Xp/Hp halo zero (b < 2B).
  {
    const int k = b & 255, which = b >> 8;
    const float* src = which ? w2 : w1;
    short* dst = which ? Wt2 : Wt1;
    const float* s = src + ((size_t)k * 256 + tid) * 9;
    const int kc = tid >> 4, ce = tid & 15;
#pragma unroll
    for (int t = 0; t < 9; ++t)
      dst[(((size_t)t * 16 + kc) * 256 + k) * 16 + ce] = (short)f2bf(s[t]);
    if (b < 2 * B) {
      short* buf = (b < B) ? (Hp + (size_t)b * PADIMG_)
                           : (Xp + (size_t)(b - B) * PADIMG_);
      for (int q = tid; q < 260 * 32; q += 256) {
        const int p = q >> 5, seg = q & 31;
        int r, c;
        if (p < 66) { r = 0; c = p; }
        else if (p < 132) { r = 65; c = p - 66; }
        else if (p < 196) { r = p - 131; c = 0; }
        else { r = p - 195; c = 65; }
        uint4* dd = (uint4*)(buf + (size_t)(r * 66 + c) * 256);
        dd[seg] = make_uint4(0u, 0u, 0u, 0u);
      }
    }
  }
  grid.sync();

  for (int n0 = 0; n0 < N_; n0 += B) {
    const int nb = (N_ - n0 < B) ? (N_ - n0) : B;
    const int swz = (nb % 8 == 0) ? 1 : 0;
    const float* xn = x + (size_t)n0 * IMG_;
    unsigned char* mn = mask + n0 * HW_;

    // xpad phase: 64*nb units over 512 blocks.
    for (int u = b; u < 64 * nb; u += 512) xpad_unit(xn, wm, bm, Xp, mn, u, sm);
    grid.sync();
    // conv0 phase: 32*nb units, one per block.
    if (b < 32 * nb)
      conv_unit(b, swz, Xp, Wt1, mn, nullptr, Hp, nullptr, 0, sm);
    grid.sync();
    // conv1 phase.
    if (b < 32 * nb)
      conv_unit(b, swz, Hp, Wt2, mn, xn, nullptr, out + (size_t)n0 * IMG_, 1,
                sm);
    grid.sync();
  }
}

// ---------------------------------------------------------------------------
extern "C" void kernel_launch(void* const* d_in, const int* in_sizes, int n_in,
                              void* d_out, int out_size, void* d_ws,
                              size_t ws_size, hipStream_t stream) {
  const float* x = (const float*)d_in[0];
  const float* w1 = (const float*)d_in[1];
  const float* w2 = (const float*)d_in[2];
  const float* wmask = (const float*)d_in[3];
  const float* bmask = (const float*)d_in[4];
  float* out = (float*)d_out;

  char* ws = (char*)d_ws;
  unsigned char* mask = (unsigned char*)ws;  // 64 KB
  short* Wt1 = (short*)(ws + 65536);         // 1.125 MiB
  short* Wt2 = Wt1 + WT_ELEMS_;              // 1.125 MiB
  const size_t fixed = 65536 + 4 * (size_t)WT_ELEMS_;  // mask + 2 Wt (bytes)
  short* Xp = (short*)(ws + fixed);

  const size_t tailpad = 32768;  // safety pad past last image
  const size_t per_img = 2 * (size_t)PADIMG_ * 2;  // Xp + Hp bytes per image
  int B = (ws_size > fixed + tailpad)
              ? (int)((ws_size - fixed - tailpad) / per_img) : 0;
  if (B > N_) B = N_;
  if (B < 1) B = 1;
  short* Hp = Xp + (size_t)B * PADIMG_;

  // Cooperative single-launch path.
  void* kargs[] = {(void*)&x,    (void*)&w1,  (void*)&w2,  (void*)&wmask,
                   (void*)&bmask, (void*)&out, (void*)&mask, (void*)&Wt1,
                   (void*)&Wt2,  (void*)&Xp,  (void*)&Hp,  (void*)&B};
  hipError_t err = hipLaunchCooperativeKernel(
      (const void*)mega, dim3(512), dim3(256), kargs, 0, stream);
  if (err == hipSuccess) return;

  // Fallback: round-11 4-launch path (verified 284.6us).
  wt_halo_kernel<<<512 + B, 256, 0, stream>>>(w1, w2, Wt1, Wt2, Hp);
  for (int n0 = 0; n0 < N_; n0 += B) {
    const int nb = (N_ - n0 < B) ? (N_ - n0) : B;
    const int swz = (nb % 8 == 0) ? 1 : 0;
    xpadmask_kernel<<<dim3(64, nb), 256, 0, stream>>>(
        x + (size_t)n0 * IMG_, wmask, bmask, Xp, mask + n0 * HW_);
    conv_mfma<0><<<dim3(4, 8, nb), 256, 0, stream>>>(
        Xp, Wt1, mask + n0 * HW_, nullptr, Hp, nullptr, swz);
    conv_mfma<1><<<dim3(4, 8, nb), 256, 0, stream>>>(
        Hp, Wt2, mask + n0 * HW_, x + (size_t)n0 * IMG_, nullptr,
        out + (size_t)n0 * IMG_, swz);
  }
}

// Round 13
// 287.326 us; speedup vs baseline: 2.2685x; 2.2685x over previous
//
#include <hip/hip_runtime.h>
#include <hip/hip_bf16.h>

#define C_ 256
#define H_ 64
#define W_ 64
#define N_ 16
#define HW_ 4096
#define IMG_ (C_ * HW_)          // 1048576 elems (fp32 image)
#define PADIMG_ (66 * 66 * 256)  // 1115136 shorts per padded NHWC image
#define WT_ELEMS_ (9 * 16 * 256 * 16)

typedef short bf16x8 __attribute__((ext_vector_type(8)));
typedef float f32x16 __attribute__((ext_vector_type(16)));

__device__ __forceinline__ unsigned short f2bf(float f) {
  __hip_bfloat16 h = __float2bfloat16(f);  // RTNE
  return *reinterpret_cast<unsigned short*>(&h);
}

__device__ __forceinline__ void gld_lds16(const void* g, void* l) {
  __builtin_amdgcn_global_load_lds(
      (const __attribute__((address_space(1))) void*)g,
      (__attribute__((address_space(3))) void*)l, 16, 0, 0);
}

// ---------------------------------------------------------------------------
// Fused pre-pass, one launch (round-12 lesson: do NOT merge with conv or
// use grid.sync -- block-range split of independent units only).
//   blocks [0, 64*nb)          : xpad row units (x -> padded NHWC bf16 +
//                                mask logits fp64 sign-exact + Xp halo)
//   blocks [64*nb, 64*nb+512)  : weight transform (only on first chunk)
//   blocks [64*nb+512, +B)     : Hp halo zero (only on first chunk)
// Each path is the unchanged round-11 kernel body; branch is block-uniform
// at kernel top, so no cross-path register/LDS coupling (v10/v12 failure
// modes avoided: no big acc state, no divergent inlined bodies).
// ---------------------------------------------------------------------------
__global__ __launch_bounds__(256) void pre_kernel(
    const float* __restrict__ x, const float* __restrict__ wm,
    const float* __restrict__ bm, short* __restrict__ Xp,
    unsigned char* __restrict__ mask, const float* __restrict__ w1,
    const float* __restrict__ w2, short* __restrict__ Wt1,
    short* __restrict__ Wt2, short* __restrict__ Hp, int nxpad) {
  const int b = blockIdx.x;
  const int tid = threadIdx.x;
  if (b < nxpad) {
    // ---- xpad unit (row h of image img), round-11 float4 version ----
    __shared__ unsigned short lds[64 * 260];  // [px][ch], pad 260
    __shared__ double dsum[16][64];           // [cg][px] fp64 partials
    __shared__ float wms[256];
    const int h = b & 63, img = b >> 6;
    const int pxq = tid & 15, cg = tid >> 4;
    const int p0 = pxq * 4;
    wms[tid] = wm[tid];
    __syncthreads();
    const float* xi = x + (size_t)img * IMG_ + h * 64;
    double s0 = 0.0, s1 = 0.0, s2 = 0.0, s3 = 0.0;
#pragma unroll
    for (int i = 0; i < 16; ++i) {
      const int c = cg * 16 + i;
      const float4 v = *(const float4*)&xi[(size_t)c * HW_ + p0];
      lds[(p0 + 0) * 260 + c] = f2bf(v.x);
      lds[(p0 + 1) * 260 + c] = f2bf(v.y);
      lds[(p0 + 2) * 260 + c] = f2bf(v.z);
      lds[(p0 + 3) * 260 + c] = f2bf(v.w);
      const double wmc = (double)wms[c];
      s0 += (double)v.x * wmc;
      s1 += (double)v.y * wmc;
      s2 += (double)v.z * wmc;
      s3 += (double)v.w * wmc;
    }
    dsum[cg][p0 + 0] = s0;
    dsum[cg][p0 + 1] = s1;
    dsum[cg][p0 + 2] = s2;
    dsum[cg][p0 + 3] = s3;
    __syncthreads();
    short* Xpimg = Xp + (size_t)img * PADIMG_;
    short* Xpi = Xpimg + ((h + 1) * 66 + 1) * 256;
    const int wv = tid >> 6, wl = tid & 63;
#pragma unroll
    for (int j = 0; j < 16; ++j) {
      int w = j * 4 + wv;
      int c4 = wl * 4;
      uint2 d = *(const uint2*)&lds[w * 260 + c4];
      *(uint2*)&Xpi[(size_t)w * 256 + c4] = d;
    }
    if (tid < 128) {  // Xp halo: left/right cols of this padded row
      const int side = tid >> 6;
      const int e = (tid & 63) * 4;
      *(uint2*)&Xpimg[((size_t)(h + 1) * 66 + side * 65) * 256 + e] =
          make_uint2(0u, 0u);
    }
    if (h == 0 || h == 63) {  // Xp halo: full top/bottom padded rows
      uint2* rowp = (uint2*)(Xpimg + (size_t)((h == 0) ? 0 : 65) * 66 * 256);
      for (int o = tid; o < 66 * 256 / 4; o += 256)
        rowp[o] = make_uint2(0u, 0u);
    }
    if (tid < 64) {
      double t = (double)bm[0];
#pragma unroll
      for (int g = 0; g < 16; ++g) t += dsum[g][tid];
      mask[img * HW_ + h * 64 + tid] = (t > 0.0) ? 1 : 0;
    }
  } else if (b < nxpad + 512) {
    // ---- weight transform: Wt[t][kc][k][c16] = bf16(w[k][kc*16+c16][t])
    const int bb = b - nxpad;
    const int k = bb & 255, which = bb >> 8;
    const float* src = which ? w2 : w1;
    short* dst = which ? Wt2 : Wt1;
    const float* s = src + ((size_t)k * 256 + tid) * 9;
    const int kc = tid >> 4, ce = tid & 15;
#pragma unroll
    for (int t = 0; t < 9; ++t)
      dst[(((size_t)t * 16 + kc) * 256 + k) * 16 + ce] = (short)f2bf(s[t]);
  } else {
    // ---- Hp halo zero for image (b - nxpad - 512) ----
    const int img = b - nxpad - 512;
    short* Hpi = Hp + (size_t)img * PADIMG_;
    for (int q = tid; q < 260 * 32; q += 256) {
      const int p = q >> 5, seg = q & 31;
      int r, c;
      if (p < 66) { r = 0; c = p; }
      else if (p < 132) { r = 65; c = p - 66; }
      else if (p < 196) { r = p - 131; c = 0; }
      else { r = p - 195; c = 65; }
      uint4* d = (uint4*)(Hpi + (size_t)(r * 66 + c) * 256);
      d[seg] = make_uint4(0u, 0u, 0u, 0u);
    }
  }
}

// ---------------------------------------------------------------------------
// Implicit-GEMM 3x3 conv (v9/v11 verified K-loop, 88-91us/dispatch; FROZEN).
// 5 structural variants converged 87-91us (rounds 5-10); tap de-phasing
// falsified in both runtime (v8) and compile-time (v10) forms; cooperative
// fusion falsified (v12: spills + phase serialization).
// Block: 64 out-ch x 512 px, 4 waves x 256 thr, wave owns 2 rows;
// acc[2 ch][4 px] = 128 AGPR, ~128 VGPR -> 2 waves/SIMD, 2 blocks/CU.
// W+B double-buffered LDS (79104 B); stage burst at kk top (10 gld_lds16
// per wave); single end-of-kk vmcnt(0)+s_barrier; 1-tap LDS lookahead with
// compile-time offsets; per-tap {2 a-reads + 4 b-reads -> 8 MFMA}.
// EPI 0: dstH[padded NHWC] = g ? relu(acc) : 0  (g = 3x3 OR mask, fused dil)
// EPI 1: dstF[NCHW fp32]   = xres + (g ? relu(acc):0)  (g = std mask)
// ---------------------------------------------------------------------------
#define BBUF 10560   // shorts per B buffer (2 K-halves x 660 slots x 8)
#define WOFF 21120   // 2 * BBUF
#define WBUF 9216    // shorts per W buffer (9 taps x 2 ihalf x 64 ch x 8)

__device__ __forceinline__ void stage_BW(short* sm, int buf, const short* Xb,
                                         const short* Wg, int ch0, int kc,
                                         int wave, int lane) {
  short* Bd = sm + buf * BBUF;
  short* Wd = sm + WOFF + buf * WBUF;
  const int ko = kc * 16;
#pragma unroll
  for (int q = 0; q < 10; ++q) {
    const int n = wave + 4 * q;
    if (n < 22) {
      // B: 11 insts per K-half; inst i<10 covers slots 64i..64i+63, inst 10
      // covers 596..659 (overlaps inst 9, identical bytes -> benign).
      const int h = (n >= 11) ? 1 : 0;
      const int i = n - h * 11;
      const int row0 = (i < 10) ? i * 64 : 596;
      gld_lds16(Xb + (size_t)(row0 + lane) * 256 + ko + h * 8,
                Bd + h * 5280 + row0 * 8);
    } else {
      // W inst m=n-22: t = m>>1, ihalf = m&1; 64 lanes cover 32 ch x 2 khalf.
      const int m = n - 22;
      const int t = m >> 1, ih = m & 1;
      gld_lds16(Wg + (((size_t)t * 16 + kc) * 256 + ch0 + ih * 32 +
                      (lane & 31)) * 16 + (lane >> 5) * 8,
                Wd + (t * 2 + ih) * 512);
    }
  }
}

template <int EPI>
__global__ __launch_bounds__(256, 2) void conv_mfma(
    const short* __restrict__ src, const short* __restrict__ Wt,
    const unsigned char* __restrict__ gate, const float* __restrict__ xres,
    short* __restrict__ dstH, float* __restrict__ dstF, int swz) {
  __shared__ __align__(16) short sm[2 * BBUF + 2 * WBUF];  // 79104 B

  const int tid = threadIdx.x;
  const int lane = tid & 63, wave = tid >> 6;  // 4 waves
  const int ln31 = lane & 31, kh = lane >> 5;

  // Block decode; swizzled path groups the 4 ch-sibling blocks on one XCD.
  int bx, by, bz;
  {
    int d = blockIdx.x + 4 * (blockIdx.y + 8 * blockIdx.z);
    if (swz) {
      int k = d & 7, j = d >> 3;
      bx = j & 3;
      by = (j >> 2) & 7;
      bz = ((j >> 5) << 3) + k;
    } else {
      bx = blockIdx.x;
      by = blockIdx.y;
      bz = blockIdx.z;
    }
  }
  const int ch0 = bx * 64;
  const int h0 = by * 8;
  const int img = bz;

  const short* Xb = src + (size_t)img * PADIMG_ + (size_t)(h0 * 66) * 256;

  f32x16 acc[2][4];
#pragma unroll
  for (int i = 0; i < 2; ++i)
#pragma unroll
    for (int j = 0; j < 4; ++j)
#pragma unroll
      for (int e = 0; e < 16; ++e) acc[i][j][e] = 0.f;

  // Prologue: stage k-chunk 0 into buf 0.
  stage_BW(sm, 0, Xb, Wt, ch0, 0, wave, lane);
  asm volatile("s_waitcnt vmcnt(0)\n\ts_barrier" ::: "memory");

  for (int kk = 0; kk < 16; ++kk) {
    const int cur = kk & 1;
    // Stage next k-chunk; latency hides under this kk's pure-LDS compute.
    if (kk < 15) stage_BW(sm, cur ^ 1, Xb, Wt, ch0, kk + 1, wave, lane);

    // Per-thread read bases (compile-time offsets from here on).
    // Wave owns padded rows wave*2 + (j>>1) + dy, cols (j&1)*32 + dx.
    const short* Bth = sm + cur * BBUF + kh * 5280 + (wave * 132 + ln31) * 8;
    const short* Wth = sm + WOFF + cur * WBUF + (kh * 32 + ln31) * 8;

    bf16x8 ac[2], bc[4], an[2], bn[4];
#pragma unroll
    for (int i = 0; i < 2; ++i)  // tap 0 frags
      ac[i] = *(const bf16x8*)(Wth + i * 512);
#pragma unroll
    for (int j = 0; j < 4; ++j)
      bc[j] = *(const bf16x8*)(Bth + ((j >> 1) * 66 + (j & 1) * 32) * 8);

#pragma unroll
    for (int t = 0; t < 9; ++t) {
      if (t < 8) {  // 1-tap lookahead (pure LDS, compile-time offsets)
        const int dy = (t + 1) / 3, dx = (t + 1) % 3;
#pragma unroll
        for (int i = 0; i < 2; ++i)
          an[i] = *(const bf16x8*)(Wth + ((t + 1) * 2 + i) * 512);
#pragma unroll
        for (int j = 0; j < 4; ++j)
          bn[j] = *(const bf16x8*)(Bth +
                                   (((j >> 1) + dy) * 66 + (j & 1) * 32 + dx) * 8);
      }
      __builtin_amdgcn_s_setprio(1);
#pragma unroll
      for (int j = 0; j < 4; ++j) {
        acc[0][j] = __builtin_amdgcn_mfma_f32_32x32x16_bf16(ac[0], bc[j],
                                                            acc[0][j], 0, 0, 0);
        acc[1][j] = __builtin_amdgcn_mfma_f32_32x32x16_bf16(ac[1], bc[j],
                                                            acc[1][j], 0, 0, 0);
      }
      __builtin_amdgcn_s_setprio(0);
      if (t < 8) {
#pragma unroll
        for (int i = 0; i < 2; ++i) ac[i] = an[i];
#pragma unroll
        for (int j = 0; j < 4; ++j) bc[j] = bn[j];
      }
    }
    if (kk < 15)
      asm volatile("s_waitcnt vmcnt(0)\n\ts_barrier" ::: "memory");
  }

  // Epilogue. 32x32 D layout: col(pixel)=lane&31, row(ch)=(reg&3)+8*(reg>>2)
  // +4*(lane>>5)  => reg group rg gives 4 consecutive channels.
  const int rb = h0 + wave * 2;
#pragma unroll
  for (int j = 0; j < 4; ++j) {
    const int r = rb + (j >> 1);
    const int col = (j & 1) * 32 + ln31;
    const int pidx = r * 64 + col;
    unsigned int g;
    if (EPI == 0) {
      // fused dilation: 3x3 OR of std mask around (r,col)
      g = 0;
#pragma unroll
      for (int dy = -1; dy <= 1; ++dy) {
        const int rr = r + dy;
        if (rr < 0 || rr >= H_) continue;
#pragma unroll
        for (int dx = -1; dx <= 1; ++dx) {
          const int cc = col + dx;
          if (cc < 0 || cc >= W_) continue;
          g |= gate[img * HW_ + rr * W_ + cc];
        }
      }
    } else {
      g = gate[img * HW_ + pidx];
    }
#pragma unroll
    for (int i = 0; i < 2; ++i) {
      const f32x16 v = acc[i][j];
#pragma unroll
      for (int rg = 0; rg < 4; ++rg) {
        const int ch = ch0 + i * 32 + rg * 8 + kh * 4;
        float e0 = g ? fmaxf(v[rg * 4 + 0], 0.f) : 0.f;
        float e1 = g ? fmaxf(v[rg * 4 + 1], 0.f) : 0.f;
        float e2 = g ? fmaxf(v[rg * 4 + 2], 0.f) : 0.f;
        float e3 = g ? fmaxf(v[rg * 4 + 3], 0.f) : 0.f;
        if (EPI == 0) {
          uint2 u;
          u.x = (unsigned int)f2bf(e0) | ((unsigned int)f2bf(e1) << 16);
          u.y = (unsigned int)f2bf(e2) | ((unsigned int)f2bf(e3) << 16);
          short* dp = dstH + (size_t)img * PADIMG_ +
                      ((size_t)((r + 1) * 66 + (col + 1))) * 256 + ch;
          *(uint2*)dp = u;
        } else {
          size_t o = (size_t)img * IMG_ + (size_t)ch * HW_ + pidx;
          dstF[o] = xres[o] + e0;
          dstF[o + HW_] = xres[o + HW_] + e1;
          dstF[o + 2 * HW_] = xres[o + 2 * HW_] + e2;
          dstF[o + 3 * HW_] = xres[o + 3 * HW_] + e3;
        }
      }
    }
  }
}

// ---------------------------------------------------------------------------
extern "C" void kernel_launch(void* const* d_in, const int* in_sizes, int n_in,
                              void* d_out, int out_size, void* d_ws,
                              size_t ws_size, hipStream_t stream) {
  const float* x = (const float*)d_in[0];
  const float* w1 = (const float*)d_in[1];
  const float* w2 = (const float*)d_in[2];
  const float* wmask = (const float*)d_in[3];
  const float* bmask = (const float*)d_in[4];
  float* out = (float*)d_out;

  char* ws = (char*)d_ws;
  unsigned char* mask = (unsigned char*)ws;  // 64 KB
  short* Wt1 = (short*)(ws + 65536);         // 1.125 MiB
  short* Wt2 = Wt1 + WT_ELEMS_;              // 1.125 MiB
  const size_t fixed = 65536 + 4 * (size_t)WT_ELEMS_;  // mask + 2 Wt (bytes)
  short* Xp = (short*)(ws + fixed);

  const size_t tailpad = 32768;  // safety pad past last image
  const size_t per_img = 2 * (size_t)PADIMG_ * 2;  // Xp + Hp bytes per image
  int B = (ws_size > fixed + tailpad)
              ? (int)((ws_size - fixed - tailpad) / per_img) : 0;
  if (B > N_) B = N_;
  if (B < 1) B = 1;
  short* Hp = Xp + (size_t)B * PADIMG_;

  for (int n0 = 0; n0 < N_; n0 += B) {
    const int nb = (N_ - n0 < B) ? (N_ - n0) : B;
    const int swz = (nb % 8 == 0) ? 1 : 0;
    const int nxpad = 64 * nb;
    // First chunk also does the weight transform + Hp halo zero.
    const int extra = (n0 == 0) ? (512 + B) : 0;
    pre_kernel<<<nxpad + extra, 256, 0, stream>>>(
        x + (size_t)n0 * IMG_, wmask, bmask, Xp, mask + n0 * HW_, w1, w2, Wt1,
        Wt2, Hp, nxpad);
    conv_mfma<0><<<dim3(4, 8, nb), 256, 0, stream>>>(
        Xp, Wt1, mask + n0 * HW_, nullptr, Hp, nullptr, swz);
    conv_mfma<1><<<dim3(4, 8, nb), 256, 0, stream>>>(
        Hp, Wt2, mask + n0 * HW_, x + (size_t)n0 * IMG_, nullptr,
        out + (size_t)n0 * IMG_, swz);
  }
}

// Round 14
// 282.214 us; speedup vs baseline: 2.3096x; 1.0181x over previous
//
#include <hip/hip_runtime.h>
#include <hip/hip_bf16.h>

#define C_ 256
#define H_ 64
#define W_ 64
#define N_ 16
#define HW_ 4096
#define IMG_ (C_ * HW_)          // 1048576 elems (fp32 image)
#define PADIMG_ (66 * 66 * 256)  // 1115136 shorts per padded NHWC image
#define WT_ELEMS_ (9 * 16 * 256 * 16)

typedef short bf16x8 __attribute__((ext_vector_type(8)));
typedef float f32x16 __attribute__((ext_vector_type(16)));

__device__ __forceinline__ unsigned short f2bf(float f) {
  __hip_bfloat16 h = __float2bfloat16(f);  // RTNE
  return *reinterpret_cast<unsigned short*>(&h);
}

__device__ __forceinline__ void gld_lds16(const void* g, void* l) {
  __builtin_amdgcn_global_load_lds(
      (const __attribute__((address_space(1))) void*)g,
      (__attribute__((address_space(3))) void*)l, 16, 0, 0);
}

// ---------------------------------------------------------------------------
// Fused pre-pass, one launch (block-range split of independent units; no
// grid.sync, no shared code paths -- v12's failure modes avoided).
//   blocks [0, 64*nb)          : xpad row units
//   blocks [64*nb, 64*nb+512)  : weight transform (first chunk only)
//   blocks [64*nb+512, +B)     : Hp halo zero (first chunk only)
// xpad v3 (round-13 analysis): the old LDS transpose write was 16-way
// bank-conflicted (banks = 8*(pxq+cg) mod 32 -> 4 banks x 16 lanes, for
// EVERY one of 64 scalar ds_write_b16 per thread). A thread already holds
// 4px x 16ch in registers -> write NHWC directly with 2 global_store_
// dwordx4 per px (64B-contiguous segments, coalesced). No LDS transpose at
// all; LDS keeps only the [16][64] fp64-partials reduce (summation order
// identical to the verified version -> bit-exact mask).
// ---------------------------------------------------------------------------
__global__ __launch_bounds__(256) void pre_kernel(
    const float* __restrict__ x, const float* __restrict__ wm,
    const float* __restrict__ bm, short* __restrict__ Xp,
    unsigned char* __restrict__ mask, const float* __restrict__ w1,
    const float* __restrict__ w2, short* __restrict__ Wt1,
    short* __restrict__ Wt2, short* __restrict__ Hp, int nxpad) {
  __shared__ double dsum[16][64];  // [cg][px] fp64 partials
  __shared__ float wms[256];
  const int b = blockIdx.x;
  const int tid = threadIdx.x;
  if (b < nxpad) {
    // ---- xpad unit (row h of image img) ----
    const int h = b & 63, img = b >> 6;
    const int pxq = tid & 15, cg = tid >> 4;
    const int p0 = pxq * 4;
    wms[tid] = wm[tid];
    __syncthreads();
    const float* xi = x + (size_t)img * IMG_ + h * 64;
    float4 v[16];
    double s0 = 0.0, s1 = 0.0, s2 = 0.0, s3 = 0.0;
#pragma unroll
    for (int i = 0; i < 16; ++i) {
      const int c = cg * 16 + i;
      v[i] = *(const float4*)&xi[(size_t)c * HW_ + p0];
      const double wmc = (double)wms[c];
      s0 += (double)v[i].x * wmc;
      s1 += (double)v[i].y * wmc;
      s2 += (double)v[i].z * wmc;
      s3 += (double)v[i].w * wmc;
    }
    dsum[cg][p0 + 0] = s0;
    dsum[cg][p0 + 1] = s1;
    dsum[cg][p0 + 2] = s2;
    dsum[cg][p0 + 3] = s3;
    // Direct NHWC bf16 stores from registers (no LDS transpose).
    short* Xpimg = Xp + (size_t)img * PADIMG_;
    short* Xpi = Xpimg + ((h + 1) * 66 + 1) * 256;
#pragma unroll
    for (int e = 0; e < 4; ++e) {
      unsigned int pk[8];
#pragma unroll
      for (int q = 0; q < 8; ++q) {
        const float lo = (e == 0) ? v[2 * q].x
                        : (e == 1) ? v[2 * q].y
                        : (e == 2) ? v[2 * q].z
                                   : v[2 * q].w;
        const float hi = (e == 0) ? v[2 * q + 1].x
                        : (e == 1) ? v[2 * q + 1].y
                        : (e == 2) ? v[2 * q + 1].z
                                   : v[2 * q + 1].w;
        pk[q] = (unsigned int)f2bf(lo) | ((unsigned int)f2bf(hi) << 16);
      }
      short* dp = Xpi + (size_t)(p0 + e) * 256 + cg * 16;
      *(uint4*)dp = make_uint4(pk[0], pk[1], pk[2], pk[3]);
      *(uint4*)(dp + 8) = make_uint4(pk[4], pk[5], pk[6], pk[7]);
    }
    // Xp halo: left/right columns of this padded row.
    if (tid < 128) {
      const int side = tid >> 6;
      const int e = (tid & 63) * 4;
      *(uint2*)&Xpimg[((size_t)(h + 1) * 66 + side * 65) * 256 + e] =
          make_uint2(0u, 0u);
    }
    // Xp halo: full top/bottom padded rows.
    if (h == 0 || h == 63) {
      uint2* rowp = (uint2*)(Xpimg + (size_t)((h == 0) ? 0 : 65) * 66 * 256);
      for (int o = tid; o < 66 * 256 / 4; o += 256)
        rowp[o] = make_uint2(0u, 0u);
    }
    __syncthreads();
    if (tid < 64) {
      double t = (double)bm[0];
#pragma unroll
      for (int g = 0; g < 16; ++g) t += dsum[g][tid];
      mask[img * HW_ + h * 64 + tid] = (t > 0.0) ? 1 : 0;
    }
  } else if (b < nxpad + 512) {
    // ---- weight transform: Wt[t][kc][k][c16] = bf16(w[k][kc*16+c16][t])
    const int bb = b - nxpad;
    const int k = bb & 255, which = bb >> 8;
    const float* src = which ? w2 : w1;
    short* dst = which ? Wt2 : Wt1;
    const float* s = src + ((size_t)k * 256 + tid) * 9;
    const int kc = tid >> 4, ce = tid & 15;
#pragma unroll
    for (int t = 0; t < 9; ++t)
      dst[(((size_t)t * 16 + kc) * 256 + k) * 16 + ce] = (short)f2bf(s[t]);
  } else {
    // ---- Hp halo zero for image (b - nxpad - 512) ----
    const int img = b - nxpad - 512;
    short* Hpi = Hp + (size_t)img * PADIMG_;
    for (int q = tid; q < 260 * 32; q += 256) {
      const int p = q >> 5, seg = q & 31;
      int r, c;
      if (p < 66) { r = 0; c = p; }
      else if (p < 132) { r = 65; c = p - 66; }
      else if (p < 196) { r = p - 131; c = 0; }
      else { r = p - 195; c = 65; }
      uint4* d = (uint4*)(Hpi + (size_t)(r * 66 + c) * 256);
      d[seg] = make_uint4(0u, 0u, 0u, 0u);
    }
  }
}

// ---------------------------------------------------------------------------
// Implicit-GEMM 3x3 conv (v9/v11 verified K-loop, 88-91us/dispatch; FROZEN).
// 5 structural variants converged 87-91us (rounds 5-10); tap de-phasing
// falsified in both runtime (v8) and compile-time (v10) forms; cooperative
// fusion falsified (v12: spills + phase serialization).
// Block: 64 out-ch x 512 px, 4 waves x 256 thr, wave owns 2 rows;
// acc[2 ch][4 px] = 128 AGPR, ~128 VGPR -> 2 waves/SIMD, 2 blocks/CU.
// W+B double-buffered LDS (79104 B); stage burst at kk top (10 gld_lds16
// per wave); single end-of-kk vmcnt(0)+s_barrier; 1-tap LDS lookahead with
// compile-time offsets; per-tap {2 a-reads + 4 b-reads -> 8 MFMA}.
// EPI 0: dstH[padded NHWC] = g ? relu(acc) : 0  (g = 3x3 OR mask, fused dil)
// EPI 1: dstF[NCHW fp32]   = xres + (g ? relu(acc):0)  (g = std mask)
// ---------------------------------------------------------------------------
#define BBUF 10560   // shorts per B buffer (2 K-halves x 660 slots x 8)
#define WOFF 21120   // 2 * BBUF
#define WBUF 9216    // shorts per W buffer (9 taps x 2 ihalf x 64 ch x 8)

__device__ __forceinline__ void stage_BW(short* sm, int buf, const short* Xb,
                                         const short* Wg, int ch0, int kc,
                                         int wave, int lane) {
  short* Bd = sm + buf * BBUF;
  short* Wd = sm + WOFF + buf * WBUF;
  const int ko = kc * 16;
#pragma unroll
  for (int q = 0; q < 10; ++q) {
    const int n = wave + 4 * q;
    if (n < 22) {
      // B: 11 insts per K-half; inst i<10 covers slots 64i..64i+63, inst 10
      // covers 596..659 (overlaps inst 9, identical bytes -> benign).
      const int h = (n >= 11) ? 1 : 0;
      const int i = n - h * 11;
      const int row0 = (i < 10) ? i * 64 : 596;
      gld_lds16(Xb + (size_t)(row0 + lane) * 256 + ko + h * 8,
                Bd + h * 5280 + row0 * 8);
    } else {
      // W inst m=n-22: t = m>>1, ihalf = m&1; 64 lanes cover 32 ch x 2 khalf.
      const int m = n - 22;
      const int t = m >> 1, ih = m & 1;
      gld_lds16(Wg + (((size_t)t * 16 + kc) * 256 + ch0 + ih * 32 +
                      (lane & 31)) * 16 + (lane >> 5) * 8,
                Wd + (t * 2 + ih) * 512);
    }
  }
}

template <int EPI>
__global__ __launch_bounds__(256, 2) void conv_mfma(
    const short* __restrict__ src, const short* __restrict__ Wt,
    const unsigned char* __restrict__ gate, const float* __restrict__ xres,
    short* __restrict__ dstH, float* __restrict__ dstF, int swz) {
  __shared__ __align__(16) short sm[2 * BBUF + 2 * WBUF];  // 79104 B

  const int tid = threadIdx.x;
  const int lane = tid & 63, wave = tid >> 6;  // 4 waves
  const int ln31 = lane & 31, kh = lane >> 5;

  // Block decode; swizzled path groups the 4 ch-sibling blocks on one XCD.
  int bx, by, bz;
  {
    int d = blockIdx.x + 4 * (blockIdx.y + 8 * blockIdx.z);
    if (swz) {
      int k = d & 7, j = d >> 3;
      bx = j & 3;
      by = (j >> 2) & 7;
      bz = ((j >> 5) << 3) + k;
    } else {
      bx = blockIdx.x;
      by = blockIdx.y;
      bz = blockIdx.z;
    }
  }
  const int ch0 = bx * 64;
  const int h0 = by * 8;
  const int img = bz;

  const short* Xb = src + (size_t)img * PADIMG_ + (size_t)(h0 * 66) * 256;

  f32x16 acc[2][4];
#pragma unroll
  for (int i = 0; i < 2; ++i)
#pragma unroll
    for (int j = 0; j < 4; ++j)
#pragma unroll
      for (int e = 0; e < 16; ++e) acc[i][j][e] = 0.f;

  // Prologue: stage k-chunk 0 into buf 0.
  stage_BW(sm, 0, Xb, Wt, ch0, 0, wave, lane);
  asm volatile("s_waitcnt vmcnt(0)\n\ts_barrier" ::: "memory");

  for (int kk = 0; kk < 16; ++kk) {
    const int cur = kk & 1;
    // Stage next k-chunk; latency hides under this kk's pure-LDS compute.
    if (kk < 15) stage_BW(sm, cur ^ 1, Xb, Wt, ch0, kk + 1, wave, lane);

    // Per-thread read bases (compile-time offsets from here on).
    // Wave owns padded rows wave*2 + (j>>1) + dy, cols (j&1)*32 + dx.
    const short* Bth = sm + cur * BBUF + kh * 5280 + (wave * 132 + ln31) * 8;
    const short* Wth = sm + WOFF + cur * WBUF + (kh * 32 + ln31) * 8;

    bf16x8 ac[2], bc[4], an[2], bn[4];
#pragma unroll
    for (int i = 0; i < 2; ++i)  // tap 0 frags
      ac[i] = *(const bf16x8*)(Wth + i * 512);
#pragma unroll
    for (int j = 0; j < 4; ++j)
      bc[j] = *(const bf16x8*)(Bth + ((j >> 1) * 66 + (j & 1) * 32) * 8);

#pragma unroll
    for (int t = 0; t < 9; ++t) {
      if (t < 8) {  // 1-tap lookahead (pure LDS, compile-time offsets)
        const int dy = (t + 1) / 3, dx = (t + 1) % 3;
#pragma unroll
        for (int i = 0; i < 2; ++i)
          an[i] = *(const bf16x8*)(Wth + ((t + 1) * 2 + i) * 512);
#pragma unroll
        for (int j = 0; j < 4; ++j)
          bn[j] = *(const bf16x8*)(Bth +
                                   (((j >> 1) + dy) * 66 + (j & 1) * 32 + dx) * 8);
      }
      __builtin_amdgcn_s_setprio(1);
#pragma unroll
      for (int j = 0; j < 4; ++j) {
        acc[0][j] = __builtin_amdgcn_mfma_f32_32x32x16_bf16(ac[0], bc[j],
                                                            acc[0][j], 0, 0, 0);
        acc[1][j] = __builtin_amdgcn_mfma_f32_32x32x16_bf16(ac[1], bc[j],
                                                            acc[1][j], 0, 0, 0);
      }
      __builtin_amdgcn_s_setprio(0);
      if (t < 8) {
#pragma unroll
        for (int i = 0; i < 2; ++i) ac[i] = an[i];
#pragma unroll
        for (int j = 0; j < 4; ++j) bc[j] = bn[j];
      }
    }
    if (kk < 15)
      asm volatile("s_waitcnt vmcnt(0)\n\ts_barrier" ::: "memory");
  }

  // Epilogue. 32x32 D layout: col(pixel)=lane&31, row(ch)=(reg&3)+8*(reg>>2)
  // +4*(lane>>5)  => reg group rg gives 4 consecutive channels.
  const int rb = h0 + wave * 2;
#pragma unroll
  for (int j = 0; j < 4; ++j) {
    const int r = rb + (j >> 1);
    const int col = (j & 1) * 32 + ln31;
    const int pidx = r * 64 + col;
    unsigned int g;
    if (EPI == 0) {
      // fused dilation: 3x3 OR of std mask around (r,col)
      g = 0;
#pragma unroll
      for (int dy = -1; dy <= 1; ++dy) {
        const int rr = r + dy;
        if (rr < 0 || rr >= H_) continue;
#pragma unroll
        for (int dx = -1; dx <= 1; ++dx) {
          const int cc = col + dx;
          if (cc < 0 || cc >= W_) continue;
          g |= gate[img * HW_ + rr * W_ + cc];
        }
      }
    } else {
      g = gate[img * HW_ + pidx];
    }
#pragma unroll
    for (int i = 0; i < 2; ++i) {
      const f32x16 v = acc[i][j];
#pragma unroll
      for (int rg = 0; rg < 4; ++rg) {
        const int ch = ch0 + i * 32 + rg * 8 + kh * 4;
        float e0 = g ? fmaxf(v[rg * 4 + 0], 0.f) : 0.f;
        float e1 = g ? fmaxf(v[rg * 4 + 1], 0.f) : 0.f;
        float e2 = g ? fmaxf(v[rg * 4 + 2], 0.f) : 0.f;
        float e3 = g ? fmaxf(v[rg * 4 + 3], 0.f) : 0.f;
        if (EPI == 0) {
          uint2 u;
          u.x = (unsigned int)f2bf(e0) | ((unsigned int)f2bf(e1) << 16);
          u.y = (unsigned int)f2bf(e2) | ((unsigned int)f2bf(e3) << 16);
          short* dp = dstH + (size_t)img * PADIMG_ +
                      ((size_t)((r + 1) * 66 + (col + 1))) * 256 + ch;
          *(uint2*)dp = u;
        } else {
          size_t o = (size_t)img * IMG_ + (size_t)ch * HW_ + pidx;
          dstF[o] = xres[o] + e0;
          dstF[o + HW_] = xres[o + HW_] + e1;
          dstF[o + 2 * HW_] = xres[o + 2 * HW_] + e2;
          dstF[o + 3 * HW_] = xres[o + 3 * HW_] + e3;
        }
      }
    }
  }
}

// ---------------------------------------------------------------------------
extern "C" void kernel_launch(void* const* d_in, const int* in_sizes, int n_in,
                              void* d_out, int out_size, void* d_ws,
                              size_t ws_size, hipStream_t stream) {
  const float* x = (const float*)d_in[0];
  const float* w1 = (const float*)d_in[1];
  const float* w2 = (const float*)d_in[2];
  const float* wmask = (const float*)d_in[3];
  const float* bmask = (const float*)d_in[4];
  float* out = (float*)d_out;

  char* ws = (char*)d_ws;
  unsigned char* mask = (unsigned char*)ws;  // 64 KB
  short* Wt1 = (short*)(ws + 65536);         // 1.125 MiB
  short* Wt2 = Wt1 + WT_ELEMS_;              // 1.125 MiB
  const size_t fixed = 65536 + 4 * (size_t)WT_ELEMS_;  // mask + 2 Wt (bytes)
  short* Xp = (short*)(ws + fixed);

  const size_t tailpad = 32768;  // safety pad past last image
  const size_t per_img = 2 * (size_t)PADIMG_ * 2;  // Xp + Hp bytes per image
  int B = (ws_size > fixed + tailpad)
              ? (int)((ws_size - fixed - tailpad) / per_img) : 0;
  if (B > N_) B = N_;
  if (B < 1) B = 1;
  short* Hp = Xp + (size_t)B * PADIMG_;

  for (int n0 = 0; n0 < N_; n0 += B) {
    const int nb = (N_ - n0 < B) ? (N_ - n0) : B;
    const int swz = (nb % 8 == 0) ? 1 : 0;
    const int nxpad = 64 * nb;
    // First chunk also does the weight transform + Hp halo zero.
    const int extra = (n0 == 0) ? (512 + B) : 0;
    pre_kernel<<<nxpad + extra, 256, 0, stream>>>(
        x + (size_t)n0 * IMG_, wmask, bmask, Xp, mask + n0 * HW_, w1, w2, Wt1,
        Wt2, Hp, nxpad);
    conv_mfma<0><<<dim3(4, 8, nb), 256, 0, stream>>>(
        Xp, Wt1, mask + n0 * HW_, nullptr, Hp, nullptr, swz);
    conv_mfma<1><<<dim3(4, 8, nb), 256, 0, stream>>>(
        Hp, Wt2, mask + n0 * HW_, x + (size_t)n0 * IMG_, nullptr,
        out + (size_t)n0 * IMG_, swz);
  }
}